// Round 8
// baseline (379.884 us; speedup 1.0000x reference)
//
#include <hip/hip_runtime.h>
#include <math.h>

// FourierButterworthHFCFilter: median-fill -> Butterworth HFC (FFT2) -> percentile norm
// B=16, C=3, H=W=512. 48 channels of 262144 fp32.
// Radix-8 FFT (512 = 8^3), DIF fwd / DIT inv, XOR-swizzled LDS,
// wave-synchronous stages, compaction-based median, fused fine-percentile hist.

#define HN 512
#define WN 512
#define NPIX (HN * WN)   // 262144
#define NCH 48
#define MED_K 131071u    // (n-1)//2
#define TWOPI 6.283185307179586f
#define CAP 32768        // candidate capacity per channel (expected ~12k max)

typedef unsigned int u32;
typedef float f4v __attribute__((ext_vector_type(4)));   // for nontemporal store

// percentile virtual ranks: 0.03*(n-1)=7864.29 -> {7864,7865}; 0.97*(n-1)=254278.71
__device__ __constant__ u32 PRANKS[4] = {7864u, 7865u, 254278u, 254279u};

// base-8 digit reversal of 9-bit index
__device__ __forceinline__ int rev8_9(int i) { return ((i & 7) << 6) | (i & 56) | (i >> 6); }

// XOR-swizzled LDS index: bijective, near-floor bank behavior for all 3 radix-8 stages
__device__ __forceinline__ int swz(int e) { return e ^ ((e >> 4) & 0xF); }

#define WB() __builtin_amdgcn_wave_barrier()

__device__ __forceinline__ u32 f2key(float f) {
  u32 u = __float_as_uint(f);
  return u ^ ((u & 0x80000000u) ? 0xFFFFFFFFu : 0x80000000u);
}
__device__ __forceinline__ float key2f(u32 k) {
  u32 u = (k & 0x80000000u) ? (k ^ 0x80000000u) : ~k;
  return __uint_as_float(u);
}

__device__ __forceinline__ float2 cadd(float2 a, float2 b) { return make_float2(a.x + b.x, a.y + b.y); }
__device__ __forceinline__ float2 csub(float2 a, float2 b) { return make_float2(a.x - b.x, a.y - b.y); }
__device__ __forceinline__ float2 cmul(float2 a, float2 b) {
  return make_float2(a.x * b.x - a.y * b.y, a.x * b.y + a.y * b.x);
}

// 8-point DFT in registers. INV=false: w8 = e^{-i pi/4}; INV=true: conjugate.
template <bool INV>
__device__ __forceinline__ void dft8(float2* r) {
  const float S2 = 0.70710678118654752f;
  float2 e0, e1, e2, e3, o0, o1, o2, o3;
  {
    float2 t0 = cadd(r[0], r[4]), t1 = csub(r[0], r[4]);
    float2 t2 = cadd(r[2], r[6]), t3 = csub(r[2], r[6]);
    e0 = cadd(t0, t2); e2 = csub(t0, t2);
    if (!INV) { e1 = make_float2(t1.x + t3.y, t1.y - t3.x); e3 = make_float2(t1.x - t3.y, t1.y + t3.x); }
    else      { e1 = make_float2(t1.x - t3.y, t1.y + t3.x); e3 = make_float2(t1.x + t3.y, t1.y - t3.x); }
  }
  {
    float2 t0 = cadd(r[1], r[5]), t1 = csub(r[1], r[5]);
    float2 t2 = cadd(r[3], r[7]), t3 = csub(r[3], r[7]);
    o0 = cadd(t0, t2); o2 = csub(t0, t2);
    if (!INV) { o1 = make_float2(t1.x + t3.y, t1.y - t3.x); o3 = make_float2(t1.x - t3.y, t1.y + t3.x); }
    else      { o1 = make_float2(t1.x - t3.y, t1.y + t3.x); o3 = make_float2(t1.x + t3.y, t1.y - t3.x); }
  }
  float2 w1o, w2o, w3o;
  if (!INV) {
    w1o = make_float2(S2 * (o1.x + o1.y), S2 * (o1.y - o1.x));   // *(1-i)s
    w2o = make_float2(o2.y, -o2.x);                              // *(-i)
    w3o = make_float2(S2 * (o3.y - o3.x), -S2 * (o3.x + o3.y));  // *-(1+i)s
  } else {
    w1o = make_float2(S2 * (o1.x - o1.y), S2 * (o1.x + o1.y));   // *(1+i)s
    w2o = make_float2(-o2.y, o2.x);                              // *(+i)
    w3o = make_float2(-S2 * (o3.x + o3.y), S2 * (o3.x - o3.y));  // *(-1+i)s
  }
  r[0] = cadd(e0, o0); r[4] = csub(e0, o0);
  r[1] = cadd(e1, w1o); r[5] = csub(e1, w1o);
  r[2] = cadd(e2, w2o); r[6] = csub(e2, w2o);
  r[3] = cadd(e3, w3o); r[7] = csub(e3, w3o);
}

// multiply r[j] *= w^j with w = e^{i*ang}
__device__ __forceinline__ void twid(float2* r, float ang) {
  float sn, cs;
  __sincosf(ang, &sn, &cs);
  float2 w = make_float2(cs, sn);
  float2 wj = w;
  r[1] = cmul(r[1], wj);
  #pragma unroll
  for (int j = 2; j < 8; ++j) { wj = cmul(wj, w); r[j] = cmul(r[j], wj); }
}

// rank-find over per*256 bins (256 threads); owning thread writes outputs; ends with barrier.
__device__ void scan_find(const u32* __restrict__ h, int per, u32 rank,
                          u32* out_bin, u32* out_pref) {
  __shared__ u32 csum[256], cpre[256];
  int t = threadIdx.x;
  u32 s = 0;
  for (int i = 0; i < per; ++i) s += h[t * per + i];
  csum[t] = s;
  __syncthreads();
  if (t == 0) { u32 a = 0; for (int i = 0; i < 256; ++i) { cpre[i] = a; a += csum[i]; } }
  __syncthreads();
  if (cpre[t] <= rank && rank < cpre[t] + csum[t]) {
    u32 acc = cpre[t];
    for (int i = 0; i < per; ++i) {
      u32 c = h[t * per + i];
      if (rank < acc + c) { *out_bin = (u32)(t * per + i); *out_pref = acc; break; }
      acc += c;
    }
  }
  __syncthreads();
}

// ---------------- median pass 1: 12-bit hist (2-copy odd-stride LDS) ----------------

__global__ __launch_bounds__(256) void kmed1(const float4* __restrict__ x4, u32* __restrict__ h1) {
  int ch = blockIdx.x >> 4, s = blockIdx.x & 15;
  __shared__ u32 lh[8193];   // copy0 @0, copy1 @4097 (odd stride -> different banks)
  for (int i = threadIdx.x; i < 8193; i += 256) lh[i] = 0;
  __syncthreads();
  int co = (threadIdx.x & 1) * 4097;
  const float4* p = x4 + (size_t)ch * (NPIX / 4) + (size_t)s * (NPIX / 64);
  for (int i = threadIdx.x; i < NPIX / 64; i += 256) {
    float4 v = p[i];
    atomicAdd(&lh[(f2key(v.x) >> 20) + co], 1u);
    atomicAdd(&lh[(f2key(v.y) >> 20) + co], 1u);
    atomicAdd(&lh[(f2key(v.z) >> 20) + co], 1u);
    atomicAdd(&lh[(f2key(v.w) >> 20) + co], 1u);
  }
  __syncthreads();
  u32* h = h1 + (size_t)ch * 4096;
  for (int i = threadIdx.x; i < 4096; i += 256) {
    u32 c = lh[i] + lh[i + 4097];
    if (c) atomicAdd(&h[i], c);
  }
}

// ---- median pass 2: in-block scan of h1 -> sel1; compact matching candidates ----

__global__ __launch_bounds__(256) void kmed2(const float4* __restrict__ x4, const u32* __restrict__ h1,
                                             u32* __restrict__ cnt, u32* __restrict__ cand) {
  int ch = blockIdx.x >> 4, s = blockIdx.x & 15;
  __shared__ u32 sb, sp;
  scan_find(h1 + (size_t)ch * 4096, 16, MED_K, &sb, &sp);
  u32 sel1 = sb;
  const float4* p = x4 + (size_t)ch * (NPIX / 4) + (size_t)s * (NPIX / 64);
  u32* cl = cand + (size_t)ch * CAP;
  int lane = threadIdx.x & 63;
  for (int i = threadIdx.x; i < NPIX / 64; i += 256) {
    float4 v = p[i];
    u32 ks[4] = {f2key(v.x), f2key(v.y), f2key(v.z), f2key(v.w)};
    #pragma unroll
    for (int j = 0; j < 4; ++j) {
      bool m = (ks[j] >> 20) == sel1;
      unsigned long long mk = __ballot(m);
      if (mk) {
        int src = (int)(__ffsll(mk) - 1);
        u32 base = 0;
        if (lane == src) base = atomicAdd(&cnt[ch], (u32)__popcll(mk));
        base = (u32)__shfl((int)base, src);
        if (m) {
          u32 off = (u32)__popcll(mk & ((1ull << lane) - 1ull));
          u32 idx = base + off;
          if (idx < CAP) cl[idx] = ks[j] & 0xFFFFFu;   // low 20 bits
        }
      }
    }
  }
}

// ---- median finish: select within candidates (bits 19:8 then 7:0) ----

__global__ __launch_bounds__(256) void kmedfin(const u32* __restrict__ h1, const u32* __restrict__ cand,
                                               float* __restrict__ med) {
  int ch = blockIdx.x;
  __shared__ u32 sb, sp;
  __shared__ u32 lh[4096];
  scan_find(h1 + (size_t)ch * 4096, 16, MED_K, &sb, &sp);
  u32 sel1 = sb;
  u32 rank2 = MED_K - sp;
  u32 n = h1[(size_t)ch * 4096 + sel1];
  if (n > CAP) n = CAP;
  for (int i = threadIdx.x; i < 4096; i += 256) lh[i] = 0;
  __syncthreads();
  const u32* cl = cand + (size_t)ch * CAP;
  for (int i = threadIdx.x; i < (int)n; i += 256) atomicAdd(&lh[(cl[i] >> 8) & 0xFFFu], 1u);
  __syncthreads();
  scan_find(lh, 16, rank2, &sb, &sp);
  u32 sel2 = sb;
  u32 rank3 = rank2 - sp;
  __syncthreads();
  lh[threadIdx.x] = 0;   // first 256 bins reused
  __syncthreads();
  for (int i = threadIdx.x; i < (int)n; i += 256) {
    u32 c = cl[i];
    if (((c >> 8) & 0xFFFu) == sel2) atomicAdd(&lh[c & 0xFFu], 1u);
  }
  __syncthreads();
  if (threadIdx.x == 0) {
    u32 acc = 0, b = 0;
    for (int i = 0; i < 256; ++i) { u32 c = lh[i]; if (rank3 < acc + c) { b = (u32)i; break; } acc += c; }
    u32 key = (sel1 << 20) | (sel2 << 8) | b;
    med[ch] = key2f(key) + 0.2f;   // median_padding adds 0.2
  }
}

// ---------------- filter permute: fmp[c*HN + h] = fmap[rev8(h)][rev8(c)] / NPIX ----------------

__global__ __launch_bounds__(256) void kperm(const float* __restrict__ fmap, float* __restrict__ fmp) {
  int c = blockIdx.x;
  for (int e = threadIdx.x; e < HN; e += 256)
    fmp[(size_t)c * HN + e] = fmap[(size_t)rev8_9(e) * WN + rev8_9(c)] * (1.0f / (float)NPIX);
}

// ---------------- row forward FFT (radix-8, 1 wave = 1 row, 4 rows/block, barrier-free) ----------------

__global__ __launch_bounds__(256) void krow_fwd(const float* __restrict__ x, const float* __restrict__ mask,
                                                const float* __restrict__ med, float2* __restrict__ cbuf, int ch0) {
  int lch = blockIdx.x >> 7, rb = blockIdx.x & 127;
  int gch = ch0 + lch;
  int lane = threadIdx.x & 63, r = threadIdx.x >> 6;
  int row = rb * 4 + r;
  __shared__ float2 lds[4][512];
  float2* L = lds[r];
  float mv = med[gch];
  const float* xr = x + (size_t)gch * NPIX + (size_t)row * WN;
  const float* mr = mask + (size_t)gch * NPIX + (size_t)row * WN;
  float2 rg[8];
  #pragma unroll
  for (int m = 0; m < 8; ++m) {
    float xv = xr[lane + 64 * m], mm = mr[lane + 64 * m];
    rg[m] = make_float2(mm * xv + (1.0f - mm) * mv, 0.0f);
  }
  dft8<false>(rg);
  twid(rg, (float)lane * (-TWOPI / 512.0f));
  #pragma unroll
  for (int j = 0; j < 8; ++j) L[swz(lane + 64 * j)] = rg[j];
  WB();
  int eb = 64 * (lane >> 3) + (lane & 7);
  #pragma unroll
  for (int m = 0; m < 8; ++m) rg[m] = L[swz(eb + 8 * m)];
  dft8<false>(rg);
  twid(rg, (float)(lane & 7) * (-TWOPI / 64.0f));
  #pragma unroll
  for (int j = 0; j < 8; ++j) L[swz(eb + 8 * j)] = rg[j];
  WB();
  int pcb = (8 * lane) ^ ((lane >> 1) & 0xF);
  #pragma unroll
  for (int m = 0; m < 8; ++m) rg[m] = L[pcb ^ m];
  dft8<false>(rg);
  #pragma unroll
  for (int j = 0; j < 8; ++j) L[pcb ^ j] = rg[j];
  WB();
  float2* cb = cbuf + (size_t)lch * NPIX + (size_t)row * WN;
  #pragma unroll
  for (int q = 0; q < 4; ++q) {
    int e = 2 * (lane + 64 * q);
    int s = swz(e);
    float2 a = L[s], b = L[s ^ 1];
    *(float4*)(cb + e) = make_float4(a.x, a.y, b.x, b.y);
  }
}

// ---- fused column pass: fwd DIF + filter + inv DIT (16 cols/block, 16 waves, 64 KiB LDS) ----

__global__ __launch_bounds__(1024, 8) void kcol(float2* __restrict__ cbuf, const float* __restrict__ fmp) {
  int lch = blockIdx.x >> 5;
  int c0 = (blockIdx.x & 31) << 4;
  int tid = threadIdx.x;
  int lane = tid & 63, w = tid >> 6;   // wave w owns column c0+w
  __shared__ float2 lds[16][512];      // exactly 64 KiB
  float2* L = lds[w];
  size_t base = (size_t)lch * NPIX + c0;
  #pragma unroll
  for (int it = 0; it < 4; ++it) {
    int g = it * 1024 + tid;
    int h = g >> 3, qq = g & 7;
    float4 v = *(const float4*)(cbuf + base + (size_t)h * WN + 2 * qq);
    int sh = swz(h);
    lds[2 * qq][sh]     = make_float2(v.x, v.y);
    lds[2 * qq + 1][sh] = make_float2(v.z, v.w);
  }
  __syncthreads();
  float2 rg[8];
  int eb = 64 * (lane >> 3) + (lane & 7);
  int pcb = (8 * lane) ^ ((lane >> 1) & 0xF);
  #pragma unroll
  for (int m = 0; m < 8; ++m) rg[m] = L[swz(lane + 64 * m)];
  dft8<false>(rg);
  twid(rg, (float)lane * (-TWOPI / 512.0f));
  #pragma unroll
  for (int j = 0; j < 8; ++j) L[swz(lane + 64 * j)] = rg[j];
  WB();
  #pragma unroll
  for (int m = 0; m < 8; ++m) rg[m] = L[swz(eb + 8 * m)];
  dft8<false>(rg);
  twid(rg, (float)(lane & 7) * (-TWOPI / 64.0f));
  #pragma unroll
  for (int j = 0; j < 8; ++j) L[swz(eb + 8 * j)] = rg[j];
  WB();
  #pragma unroll
  for (int m = 0; m < 8; ++m) rg[m] = L[pcb ^ m];
  dft8<false>(rg);
  {
    const float* fp = fmp + (size_t)(c0 + w) * HN + 8 * lane;
    float4 f0 = *(const float4*)fp, f1 = *(const float4*)(fp + 4);
    rg[0].x *= f0.x; rg[0].y *= f0.x;  rg[1].x *= f0.y; rg[1].y *= f0.y;
    rg[2].x *= f0.z; rg[2].y *= f0.z;  rg[3].x *= f0.w; rg[3].y *= f0.w;
    rg[4].x *= f1.x; rg[4].y *= f1.x;  rg[5].x *= f1.y; rg[5].y *= f1.y;
    rg[6].x *= f1.z; rg[6].y *= f1.z;  rg[7].x *= f1.w; rg[7].y *= f1.w;
  }
  dft8<true>(rg);
  #pragma unroll
  for (int j = 0; j < 8; ++j) L[pcb ^ j] = rg[j];
  WB();
  #pragma unroll
  for (int m = 0; m < 8; ++m) rg[m] = L[swz(eb + 8 * m)];
  twid(rg, (float)(lane & 7) * (TWOPI / 64.0f));
  dft8<true>(rg);
  #pragma unroll
  for (int j = 0; j < 8; ++j) L[swz(eb + 8 * j)] = rg[j];
  WB();
  #pragma unroll
  for (int m = 0; m < 8; ++m) rg[m] = L[swz(lane + 64 * m)];
  twid(rg, (float)lane * (TWOPI / 512.0f));
  dft8<true>(rg);
  #pragma unroll
  for (int j = 0; j < 8; ++j) L[swz(lane + 64 * j)] = rg[j];
  __syncthreads();
  #pragma unroll
  for (int it = 0; it < 4; ++it) {
    int g = it * 1024 + tid;
    int h = g >> 3, qq = g & 7;
    int sh = swz(h);
    float2 a = lds[2 * qq][sh], b = lds[2 * qq + 1][sh];
    *(float4*)(cbuf + base + (size_t)h * WN + 2 * qq) = make_float4(a.x, a.y, b.x, b.y);
  }
}

// ---- row inverse FFT + |.| + fused 4096-bin fine percentile histogram ----

__global__ __launch_bounds__(256) void krow_inv(const float2* __restrict__ cbuf, float* __restrict__ out,
                                                u32* __restrict__ hfine, int ch0) {
  int lch = blockIdx.x >> 7, rb = blockIdx.x & 127;
  int gch = ch0 + lch;
  int lane = threadIdx.x & 63, r = threadIdx.x >> 6;
  int row = rb * 4 + r;
  __shared__ float2 lds[4][512];
  __shared__ u32 fh[4096];
  float2* L = lds[r];
  for (int i = threadIdx.x; i < 4096; i += 256) fh[i] = 0;
  __syncthreads();
  const float2* cb = cbuf + (size_t)lch * NPIX + (size_t)row * WN;
  #pragma unroll
  for (int q = 0; q < 4; ++q) {
    int e = 2 * (lane + 64 * q);
    float4 v = *(const float4*)(cb + e);
    int s = swz(e);
    L[s]     = make_float2(v.x, v.y);
    L[s ^ 1] = make_float2(v.z, v.w);
  }
  WB();
  float2 rg[8];
  int pcb = (8 * lane) ^ ((lane >> 1) & 0xF);
  #pragma unroll
  for (int m = 0; m < 8; ++m) rg[m] = L[pcb ^ m];
  dft8<true>(rg);
  #pragma unroll
  for (int j = 0; j < 8; ++j) L[pcb ^ j] = rg[j];
  WB();
  int eb = 64 * (lane >> 3) + (lane & 7);
  #pragma unroll
  for (int m = 0; m < 8; ++m) rg[m] = L[swz(eb + 8 * m)];
  twid(rg, (float)(lane & 7) * (TWOPI / 64.0f));
  dft8<true>(rg);
  #pragma unroll
  for (int j = 0; j < 8; ++j) L[swz(eb + 8 * j)] = rg[j];
  WB();
  #pragma unroll
  for (int m = 0; m < 8; ++m) rg[m] = L[swz(lane + 64 * m)];
  twid(rg, (float)lane * (TWOPI / 512.0f));
  dft8<true>(rg);
  float* orow = out + (size_t)gch * NPIX + (size_t)row * WN;
  #pragma unroll
  for (int j = 0; j < 8; ++j) {
    float mg = sqrtf(rg[j].x * rg[j].x + rg[j].y * rg[j].y);
    orow[lane + 64 * j] = mg;
    u32 bin = (u32)fminf(mg * 256.0f, 4095.0f);   // temp bin (exact: temp = k/256), clamp tail
    atomicAdd(&fh[bin], 1u);
  }
  __syncthreads();
  for (int i = threadIdx.x; i < 4096; i += 256) {
    u32 c = fh[i];
    if (c) atomicAdd(&hfine[(size_t)gch * 4096 + i], c);
  }
}

// ---------------- percentile scan (single kernel) ----------------

__global__ __launch_bounds__(256) void kpct(const u32* __restrict__ hfine,
                                            float* __restrict__ lov, float* __restrict__ invv) {
  int ch = blockIdx.x;
  __shared__ u32 sb, sp;
  __shared__ u32 bins[4];
  const u32* h = hfine + (size_t)ch * 4096;
  for (int q = 0; q < 4; ++q) {
    scan_find(h, 16, PRANKS[q], &sb, &sp);
    if (threadIdx.x == 0) bins[q] = sb;
    __syncthreads();
  }
  if (threadIdx.x == 0) {
    double vlo = 0.03 * (double)(NPIX - 1);
    double vhi = 0.97 * (double)(NPIX - 1);
    double glo = vlo - floor(vlo);
    double ghi = vhi - floor(vhi);
    double l0 = bins[0] / 256.0, l1 = bins[1] / 256.0;
    double h0 = bins[2] / 256.0, h1 = bins[3] / 256.0;
    double lo = l0 + glo * (l1 - l0);
    double hi = h0 + ghi * (h1 - h0);
    lov[ch] = (float)lo;
    invv[ch] = (float)(1.0 / (hi - lo));
  }
}

// ---------------- finalize ----------------

__global__ __launch_bounds__(256) void kfinal(float4* __restrict__ o4, const float4* __restrict__ m4,
                                              const float* __restrict__ lov, const float* __restrict__ invv) {
  size_t i = (size_t)blockIdx.x * 256 + threadIdx.x;
  int ch = (int)(i >> 16);  // 65536 float4 per channel
  float lo = lov[ch], iv = invv[ch];
  float4 o = o4[i], m = m4[i];
  f4v res;
  res.x = (o.x - lo) * iv * m.x;
  res.y = (o.y - lo) * iv * m.y;
  res.z = (o.z - lo) * iv * m.z;
  res.w = (o.w - lo) * iv * m.w;
  __builtin_nontemporal_store(res, (f4v*)&o4[i]);
}

// ---------------- launch ----------------

extern "C" void kernel_launch(void* const* d_in, const int* in_sizes, int n_in,
                              void* d_out, int out_size, void* d_ws, size_t ws_size,
                              hipStream_t stream) {
  (void)in_sizes; (void)n_in; (void)out_size;
  const float* x = (const float*)d_in[0];
  const float* mask = (const float*)d_in[1];
  const float* fmap = (const float*)d_in[2];
  float* out = (float*)d_out;
  char* ws = (char*)d_ws;

  // ---- workspace layout (bytes) ----
  size_t off = 0;
  u32* h1    = (u32*)(ws + off); off += (size_t)NCH * 4096 * 4;   // 786432
  u32* hfine = (u32*)(ws + off); off += (size_t)NCH * 4096 * 4;   // 786432
  u32* cnt   = (u32*)(ws + off); off += (size_t)NCH * 4;
  const size_t ZBYTES = off;                                      // zeroed each call
  float* med  = (float*)(ws + off); off += NCH * 4;
  float* lov  = (float*)(ws + off); off += NCH * 4;
  float* invv = (float*)(ws + off); off += NCH * 4;
  off = (off + 255) & ~(size_t)255;
  u32* cand = (u32*)(ws + off); off += (size_t)NCH * CAP * 4;     // 6.29 MB
  float* fmp = (float*)(ws + off); off += (size_t)NPIX * 4;       // permuted+prescaled filter
  off = (off + 255) & ~(size_t)255;
  float2* cbuf = (float2*)(ws + off);

  size_t avail = (ws_size > off) ? ws_size - off : 0;
  int cpc = 1;
  const int cands[6] = {16, 12, 8, 4, 2, 1};
  for (int i = 0; i < 6; ++i) {
    if ((size_t)cands[i] * NPIX * sizeof(float2) <= avail) { cpc = cands[i]; break; }
  }

  (void)hipMemsetAsync(ws, 0, ZBYTES, stream);
  kperm<<<WN, 256, 0, stream>>>(fmap, fmp);

  // median: hist -> compact -> finish (x read twice + tiny candidate pass)
  kmed1<<<NCH * 16, 256, 0, stream>>>((const float4*)x, h1);
  kmed2<<<NCH * 16, 256, 0, stream>>>((const float4*)x, h1, cnt, cand);
  kmedfin<<<NCH, 256, 0, stream>>>(h1, cand, med);

  // FFT2 -> filter -> IFFT2 -> |.| (into d_out) + fused fine percentile hist
  for (int ch0 = 0; ch0 < NCH; ch0 += cpc) {
    int cc = (NCH - ch0 < cpc) ? (NCH - ch0) : cpc;
    krow_fwd<<<cc * 128, 256, 0, stream>>>(x, mask, med, cbuf, ch0);
    kcol<<<cc * 32, 1024, 0, stream>>>(cbuf, fmp);
    krow_inv<<<cc * 128, 256, 0, stream>>>(cbuf, out, hfine, ch0);
  }

  // percentile scan + normalize
  kpct<<<NCH, 256, 0, stream>>>(hfine, lov, invv);
  kfinal<<<(NCH * NPIX / 4) / 256, 256, 0, stream>>>((float4*)out, (const float4*)mask, lov, invv);
}